// Round 14
// baseline (31.708 us; speedup 1.0000x reference)
//
#include <hip/hip_runtime.h>

// Problem constants (match reference: B=8, N=8192, D=256, M=2)
#define NN 8192
#define DD 256
#define NH (NN / 2)
#define BB 8
#define RPW 8    // output rows per wave
#define WPB 2    // waves per block (128-thread blocks, R10's proven config)
#define NBLK (BB * NN / RPW / WPB)   // 4096
#define CPX (NBLK / 8)               // 512 blocks per XCD chunk (== one batch b)

__device__ __forceinline__ float4 f4_load(const float* p) {
    return *reinterpret_cast<const float4*>(p);
}
__device__ __forceinline__ float4 f4_scale(float s, float4 v) {
    return make_float4(s * v.x, s * v.y, s * v.z, s * v.w);
}
__device__ __forceinline__ float4 f4_fma(float s, float4 v, float4 a) {
    return make_float4(fmaf(s, v.x, a.x), fmaf(s, v.y, a.y),
                       fmaf(s, v.z, a.z), fmaf(s, v.w, a.w));
}

__global__ __launch_bounds__(128) void dhhp_kernel(
    const float* __restrict__ x,
    const float* __restrict__ gl_ii, const float* __restrict__ gl_ij,
    const float* __restrict__ gl_ji, const float* __restrict__ gl_jj,
    const float* __restrict__ gu_ii, const float* __restrict__ gu_ij,
    const float* __restrict__ gu_ji, const float* __restrict__ gu_jj,
    const float* __restrict__ diag, const int* __restrict__ transform,
    float* __restrict__ out)
{
    // XCD-aware swizzle: each XCD gets a contiguous 512-block chunk == one batch.
    const int bid = blockIdx.x;
    const int swz = __builtin_amdgcn_readfirstlane((bid & 7) * CPX + (bid >> 3));
    const int b   = swz >> 9;            // 512 blocks per batch
    const int k   = swz & 511;           // block index within batch
    const int w   = __builtin_amdgcn_readfirstlane(threadIdx.x >> 6);
    // Contiguous-source mapping (transform=1): wave0 window j0=8k reads EVEN
    // source rows 16k.., wave1 window j0=NH+8k reads ODD rows 16k+1.. — the
    // block's combined read stream is one contiguous ~24KB region.
    const int j0  = __builtin_amdgcn_readfirstlane((w ? NH : 0) + (k << 3));
    const int col = (threadIdx.x & 63) << 2;         // float4 per lane
    const int tr  = *transform;

    const float* xb  = x    + (size_t)b * NN * DD;
    const float* db  = diag + (size_t)b * NN;
    const float* uii = gu_ii + (size_t)b * (NN - 1);
    const float* uij = gu_ij + (size_t)b * (NN - 1);
    const float* uji = gu_ji + (size_t)b * (NN - 1);
    const float* ujj = gu_jj + (size_t)b * (NN - 1);
    const float* lii = gl_ii + (size_t)b * (NN - 1);
    const float* lij = gl_ij + (size_t)b * (NN - 1);
    const float* lji = gl_ji + (size_t)b * (NN - 1);
    const float* ljj = gl_jj + (size_t)b * (NN - 1);
    float* ob = out + (size_t)b * NN * DD;

    auto permRow = [&](int i) -> int {
        return tr ? ((i < NH) ? (i << 1) : (((i - NH) << 1) | 1)) : i;
    };
    auto loadRowI = [&](int i) -> float4 {           // interior: no clamp
        float4 v = f4_load(xb + (size_t)permRow(i) * DD + col);
        if (!tr) v = f4_scale(db[i], v);
        return v;
    };
    auto loadRowC = [&](int i) -> float4 {           // edge: clamped
        int ic = i < 0 ? 0 : (i > NN - 1 ? NN - 1 : i);
        return loadRowI(ic);
    };
    auto yInner = [&](int i, float4 xm, float4 xc, float4 xp) -> float4 {
        float lo  = uji[i - 1];
        float cjj = ujj[i - 1];
        float dm  = cjj * uii[i];
        float hi  = cjj * uij[i];
        float4 r = f4_scale(lo, xm);
        r = f4_fma(dm, xc, r);
        r = f4_fma(hi, xp, r);
        return r;
    };
    // ghost rows (i<0 / i>N-1 after clamp) produce wrong-but-unused values
    auto yAny = [&](int i, float4 xm, float4 xc, float4 xp) -> float4 {
        int ic = i < 0 ? 0 : (i > NN - 1 ? NN - 1 : i);
        if (ic == 0)      return f4_fma(uii[0], xc, f4_scale(uij[0], xp));
        if (ic == NN - 1) return f4_fma(uji[NN - 2], xm, f4_scale(ujj[NN - 2], xc));
        return yInner(ic, xm, xc, xp);
    };
    auto zInner = [&](int j, float4 ym, float4 yc, float4 yp) -> float4 {
        float ci = lii[j];
        float lo = ci * lji[j - 1];
        float dm = ci * ljj[j - 1];
        float hi = lij[j];
        float4 r = f4_scale(lo, ym);
        r = f4_fma(dm, yc, r);
        r = f4_fma(hi, yp, r);
        return r;
    };
    auto zAny = [&](int j, float4 ym, float4 yc, float4 yp) -> float4 {
        if (j == 0)      return f4_fma(lii[0], yc, f4_scale(lij[0], yp));
        if (j == NN - 1) return f4_fma(lji[NN - 2], ym, f4_scale(ljj[NN - 2], yc));
        return zInner(j, ym, yc, yp);
    };
    auto storeRow = [&](int j, float4 z) {
        int jo;
        float4 o;
        if (tr) { o = f4_scale(db[j], z); jo = j; }
        else    { o = z; jo = (j & 1) ? (NH + (j >> 1)) : (j >> 1); }
        *reinterpret_cast<float4*>(ob + (size_t)jo * DD + col) = o;
    };

    const bool interior = (j0 >= 2) && (j0 <= NN - RPW - 2);

    float4 xr[RPW + 4];   // x[j0-2 .. j0+RPW+1]
    float4 yr[RPW + 2];   // y[j0-1 .. j0+RPW]

    if (interior) {
        #pragma unroll
        for (int t = 0; t < RPW + 4; ++t) xr[t] = loadRowI(j0 - 2 + t);
        #pragma unroll
        for (int t = 0; t < RPW + 2; ++t)
            yr[t] = yInner(j0 - 1 + t, xr[t], xr[t + 1], xr[t + 2]);
        #pragma unroll
        for (int t = 0; t < RPW; ++t)
            storeRow(j0 + t, zInner(j0 + t, yr[t], yr[t + 1], yr[t + 2]));
    } else {
        #pragma unroll
        for (int t = 0; t < RPW + 4; ++t) xr[t] = loadRowC(j0 - 2 + t);
        #pragma unroll
        for (int t = 0; t < RPW + 2; ++t)
            yr[t] = yAny(j0 - 1 + t, xr[t], xr[t + 1], xr[t + 2]);
        #pragma unroll
        for (int t = 0; t < RPW; ++t)
            storeRow(j0 + t, zAny(j0 + t, yr[t], yr[t + 1], yr[t + 2]));
    }
}

extern "C" void kernel_launch(void* const* d_in, const int* in_sizes, int n_in,
                              void* d_out, int out_size, void* d_ws, size_t ws_size,
                              hipStream_t stream) {
    const float* x     = (const float*)d_in[0];
    const float* gl_ii = (const float*)d_in[1];
    const float* gl_ij = (const float*)d_in[2];
    const float* gl_ji = (const float*)d_in[3];
    const float* gl_jj = (const float*)d_in[4];
    const float* gu_ii = (const float*)d_in[5];
    const float* gu_ij = (const float*)d_in[6];
    const float* gu_ji = (const float*)d_in[7];
    const float* gu_jj = (const float*)d_in[8];
    const float* diag  = (const float*)d_in[9];
    const int* transform = (const int*)d_in[10];
    float* out = (float*)d_out;

    dim3 grid(NBLK);      // 4096 blocks, 2 waves each (R10 grid; contiguous-source mapping)
    dim3 block(128);
    hipLaunchKernelGGL(dhhp_kernel, grid, block, 0, stream,
                       x, gl_ii, gl_ij, gl_ji, gl_jj,
                       gu_ii, gu_ij, gu_ji, gu_jj, diag, transform, out);
}

// Round 15
// 27.769 us; speedup vs baseline: 1.1419x; 1.1419x over previous
//
#include <hip/hip_runtime.h>

// Problem constants (match reference: B=8, N=8192, D=256, M=2)
// FINAL: R10 configuration — best measured (27.8 us).
// Probes exhausted: MLP (R5/R6/R7 null), r/w phasing (R8/R9 regress),
// TLP (4096x128 optimum), redundancy (R13 regress), contiguity (R14 regress).
#define NN 8192
#define DD 256
#define NH (NN / 2)
#define BB 8
#define RPW 8    // output rows per wave
#define WPB 2    // waves per block (128-thread blocks -> 4096 blocks)
#define NBLK (BB * NN / RPW / WPB)   // 4096
#define CPX (NBLK / 8)               // 512 blocks per XCD chunk (== one batch b)

__device__ __forceinline__ float4 f4_load(const float* p) {
    return *reinterpret_cast<const float4*>(p);
}
__device__ __forceinline__ float4 f4_scale(float s, float4 v) {
    return make_float4(s * v.x, s * v.y, s * v.z, s * v.w);
}
__device__ __forceinline__ float4 f4_fma(float s, float4 v, float4 a) {
    return make_float4(fmaf(s, v.x, a.x), fmaf(s, v.y, a.y),
                       fmaf(s, v.z, a.z), fmaf(s, v.w, a.w));
}

__global__ __launch_bounds__(128) void dhhp_kernel(
    const float* __restrict__ x,
    const float* __restrict__ gl_ii, const float* __restrict__ gl_ij,
    const float* __restrict__ gl_ji, const float* __restrict__ gl_jj,
    const float* __restrict__ gu_ii, const float* __restrict__ gu_ij,
    const float* __restrict__ gu_ji, const float* __restrict__ gu_jj,
    const float* __restrict__ diag, const int* __restrict__ transform,
    float* __restrict__ out)
{
    // XCD-aware swizzle: each XCD gets a contiguous 512-block chunk == one batch.
    const int bid = blockIdx.x;
    const int swz = (bid & 7) * CPX + (bid >> 3);
    int wid = swz * WPB + (threadIdx.x >> 6);
    wid = __builtin_amdgcn_readfirstlane(wid);       // wave-uniform -> SGPRs
    const int b   = wid >> 10;                       // waves per batch = NN/RPW = 1024
    const int j0  = (wid & 1023) << 3;               // * RPW
    const int col = (threadIdx.x & 63) << 2;         // float4 per lane
    const int tr  = *transform;

    const float* xb  = x    + (size_t)b * NN * DD;
    const float* db  = diag + (size_t)b * NN;
    const float* uii = gu_ii + (size_t)b * (NN - 1);
    const float* uij = gu_ij + (size_t)b * (NN - 1);
    const float* uji = gu_ji + (size_t)b * (NN - 1);
    const float* ujj = gu_jj + (size_t)b * (NN - 1);
    const float* lii = gl_ii + (size_t)b * (NN - 1);
    const float* lij = gl_ij + (size_t)b * (NN - 1);
    const float* lji = gl_ji + (size_t)b * (NN - 1);
    const float* ljj = gl_jj + (size_t)b * (NN - 1);
    float* ob = out + (size_t)b * NN * DD;

    auto permRow = [&](int i) -> int {
        return tr ? ((i < NH) ? (i << 1) : (((i - NH) << 1) | 1)) : i;
    };
    auto loadRowI = [&](int i) -> float4 {           // interior: no clamp
        float4 v = f4_load(xb + (size_t)permRow(i) * DD + col);
        if (!tr) v = f4_scale(db[i], v);
        return v;
    };
    auto loadRowC = [&](int i) -> float4 {           // edge: clamped
        int ic = i < 0 ? 0 : (i > NN - 1 ? NN - 1 : i);
        return loadRowI(ic);
    };
    auto yInner = [&](int i, float4 xm, float4 xc, float4 xp) -> float4 {
        float lo  = uji[i - 1];
        float cjj = ujj[i - 1];
        float dm  = cjj * uii[i];
        float hi  = cjj * uij[i];
        float4 r = f4_scale(lo, xm);
        r = f4_fma(dm, xc, r);
        r = f4_fma(hi, xp, r);
        return r;
    };
    // ghost rows (i<0 / i>N-1 after clamp) produce wrong-but-unused values
    auto yAny = [&](int i, float4 xm, float4 xc, float4 xp) -> float4 {
        int ic = i < 0 ? 0 : (i > NN - 1 ? NN - 1 : i);
        if (ic == 0)      return f4_fma(uii[0], xc, f4_scale(uij[0], xp));
        if (ic == NN - 1) return f4_fma(uji[NN - 2], xm, f4_scale(ujj[NN - 2], xc));
        return yInner(ic, xm, xc, xp);
    };
    auto zInner = [&](int j, float4 ym, float4 yc, float4 yp) -> float4 {
        float ci = lii[j];
        float lo = ci * lji[j - 1];
        float dm = ci * ljj[j - 1];
        float hi = lij[j];
        float4 r = f4_scale(lo, ym);
        r = f4_fma(dm, yc, r);
        r = f4_fma(hi, yp, r);
        return r;
    };
    auto zAny = [&](int j, float4 ym, float4 yc, float4 yp) -> float4 {
        if (j == 0)      return f4_fma(lii[0], yc, f4_scale(lij[0], yp));
        if (j == NN - 1) return f4_fma(lji[NN - 2], ym, f4_scale(ljj[NN - 2], yc));
        return zInner(j, ym, yc, yp);
    };
    auto storeRow = [&](int j, float4 z) {
        int jo;
        float4 o;
        if (tr) { o = f4_scale(db[j], z); jo = j; }
        else    { o = z; jo = (j & 1) ? (NH + (j >> 1)) : (j >> 1); }
        *reinterpret_cast<float4*>(ob + (size_t)jo * DD + col) = o;
    };

    const bool interior = (j0 >= 2) && (j0 <= NN - RPW - 2);

    float4 xr[RPW + 4];   // x[j0-2 .. j0+RPW+1]
    float4 yr[RPW + 2];   // y[j0-1 .. j0+RPW]

    if (interior) {
        #pragma unroll
        for (int t = 0; t < RPW + 4; ++t) xr[t] = loadRowI(j0 - 2 + t);
        #pragma unroll
        for (int t = 0; t < RPW + 2; ++t)
            yr[t] = yInner(j0 - 1 + t, xr[t], xr[t + 1], xr[t + 2]);
        #pragma unroll
        for (int t = 0; t < RPW; ++t)
            storeRow(j0 + t, zInner(j0 + t, yr[t], yr[t + 1], yr[t + 2]));
    } else {
        #pragma unroll
        for (int t = 0; t < RPW + 4; ++t) xr[t] = loadRowC(j0 - 2 + t);
        #pragma unroll
        for (int t = 0; t < RPW + 2; ++t)
            yr[t] = yAny(j0 - 1 + t, xr[t], xr[t + 1], xr[t + 2]);
        #pragma unroll
        for (int t = 0; t < RPW; ++t)
            storeRow(j0 + t, zAny(j0 + t, yr[t], yr[t + 1], yr[t + 2]));
    }
}

extern "C" void kernel_launch(void* const* d_in, const int* in_sizes, int n_in,
                              void* d_out, int out_size, void* d_ws, size_t ws_size,
                              hipStream_t stream) {
    const float* x     = (const float*)d_in[0];
    const float* gl_ii = (const float*)d_in[1];
    const float* gl_ij = (const float*)d_in[2];
    const float* gl_ji = (const float*)d_in[3];
    const float* gl_jj = (const float*)d_in[4];
    const float* gu_ii = (const float*)d_in[5];
    const float* gu_ij = (const float*)d_in[6];
    const float* gu_ji = (const float*)d_in[7];
    const float* gu_jj = (const float*)d_in[8];
    const float* diag  = (const float*)d_in[9];
    const int* transform = (const int*)d_in[10];
    float* out = (float*)d_out;

    dim3 grid(NBLK);      // 4096 blocks, 2 waves each (best measured config)
    dim3 block(128);
    hipLaunchKernelGGL(dhhp_kernel, grid, block, 0, stream,
                       x, gl_ii, gl_ij, gl_ji, gl_jj,
                       gu_ii, gu_ij, gu_ji, gu_jj, diag, transform, out);
}